// Round 1
// baseline (1574.992 us; speedup 1.0000x reference)
//
#include <hip/hip_runtime.h>
#include <hip/hip_bf16.h>

// GCN forward: 4 layers of x = relu( D^-1/2 (A+I) D^-1/2 (x W) + b + x )
// Strategy:
//   g   = dis ⊙ (x @ W)              (per-row pre-scale by deg^-1/2)
//   out = relu( dis[v]*(g[v] + Σ_{e:dst=v} g[src_e]) + b + x_prev[v] )
// CSR-by-dst built once per call -> aggregation is pure gather (no fp atomics).

#define EMB 128

// ---------- setup kernels ----------

__global__ void zero_int(int* __restrict__ p, int n) {
    int i = blockIdx.x * 256 + threadIdx.x;
    if (i < n) p[i] = 0;
}

__global__ void count_deg(const int* __restrict__ ei, int* __restrict__ cnt, int ne) {
    int e = blockIdx.x * 256 + threadIdx.x;
    if (e >= ne) return;
    atomicAdd(&cnt[ei[ne + e]], 1);   // dst row of edge_index
}

__global__ __launch_bounds__(256) void block_sums(const int* __restrict__ cnt,
                                                  int* __restrict__ bs, int n) {
    __shared__ int sm[256];
    int i = blockIdx.x * 256 + threadIdx.x;
    sm[threadIdx.x] = (i < n) ? cnt[i] : 0;
    __syncthreads();
    for (int s = 128; s > 0; s >>= 1) {
        if (threadIdx.x < s) sm[threadIdx.x] += sm[threadIdx.x + s];
        __syncthreads();
    }
    if (threadIdx.x == 0) bs[blockIdx.x] = sm[0];
}

// single block: inclusive scan of nb (<=256) block sums -> exclusive offsets
__global__ __launch_bounds__(256) void scan_bs(const int* __restrict__ bs,
                                               int* __restrict__ boff, int nb) {
    __shared__ int sm[256];
    int t = threadIdx.x;
    sm[t] = (t < nb) ? bs[t] : 0;
    __syncthreads();
    for (int off = 1; off < 256; off <<= 1) {
        int y = (t >= off) ? sm[t - off] : 0;
        __syncthreads();
        sm[t] += y;
        __syncthreads();
    }
    if (t < nb) boff[t] = (t == 0) ? 0 : sm[t - 1];
}

__global__ __launch_bounds__(256) void scan_write(const int* __restrict__ cnt,
                                                  const int* __restrict__ boff,
                                                  int* __restrict__ row_start,
                                                  int* __restrict__ cursor,
                                                  float* __restrict__ dis, int n) {
    __shared__ int sm[256];
    int t = threadIdx.x;
    int i = blockIdx.x * 256 + t;
    int c = (i < n) ? cnt[i] : 0;
    sm[t] = c;
    __syncthreads();
    for (int off = 1; off < 256; off <<= 1) {
        int y = (t >= off) ? sm[t - off] : 0;
        __syncthreads();
        sm[t] += y;
        __syncthreads();
    }
    if (i < n) {
        int excl = boff[blockIdx.x] + sm[t] - c;
        row_start[i] = excl;
        cursor[i]    = excl;
        dis[i] = rsqrtf((float)(c + 1));   // +1 self-loop; always > 0
        if (i == n - 1) row_start[n] = boff[blockIdx.x] + sm[t];
    }
}

__global__ void fill_col(const int* __restrict__ ei, int* __restrict__ cursor,
                         int* __restrict__ colv, int ne) {
    int e = blockIdx.x * 256 + threadIdx.x;
    if (e >= ne) return;
    int s = ei[e];
    int d = ei[ne + e];
    int p = atomicAdd(&cursor[d], 1);
    colv[p] = s;
}

// ---------- per-layer kernels ----------

// g[r] = dis[r] * (X[r] @ W)   ; W staged in LDS (64KB), one wave per row.
__global__ __launch_bounds__(256) void gemm_scale(const float* __restrict__ X,
                                                  const float* __restrict__ W,
                                                  const float* __restrict__ dis,
                                                  float* __restrict__ g, int nrows) {
    __shared__ float w[EMB * EMB];
    const float4* W4 = (const float4*)W;
    float4* w4 = (float4*)w;
    #pragma unroll
    for (int i = 0; i < 16; ++i)
        w4[i * 256 + threadIdx.x] = W4[i * 256 + threadIdx.x];
    __syncthreads();

    int lane = threadIdx.x & 63;
    int wid  = threadIdx.x >> 6;
    int gw   = blockIdx.x * 4 + wid;
    int stride = gridDim.x * 4;

    for (int r = gw; r < nrows; r += stride) {
        float xa = X[r * EMB + lane];        // k = lane
        float xb = X[r * EMB + 64 + lane];   // k = 64 + lane
        // lane owns output dims d0 = 2*lane, 2*lane+1 (contiguous -> ds_read_b64)
        float acc0 = 0.f, acc1 = 0.f;
        int d0 = 2 * lane;
        #pragma unroll
        for (int k = 0; k < 64; ++k) {
            float xv = __shfl(xa, k, 64);
            float2 wv = *(const float2*)&w[k * EMB + d0];
            acc0 += xv * wv.x;
            acc1 += xv * wv.y;
        }
        #pragma unroll
        for (int k = 0; k < 64; ++k) {
            float xv = __shfl(xb, k, 64);
            float2 wv = *(const float2*)&w[(64 + k) * EMB + d0];
            acc0 += xv * wv.x;
            acc1 += xv * wv.y;
        }
        float dv = dis[r];
        ((float2*)g)[r * 64 + lane] = make_float2(dv * acc0, dv * acc1);
    }
}

// out[v] = relu( dis[v]*(g[v] + sum_{e in CSR[v]} g[col[e]]) + b + xprev[v] )
__global__ __launch_bounds__(256) void aggregate(const float* __restrict__ g,
                                                 const int* __restrict__ colv,
                                                 const int* __restrict__ row_start,
                                                 const float* __restrict__ dis,
                                                 const float* __restrict__ bias,
                                                 const float* __restrict__ xprev,
                                                 float* __restrict__ xout, int n) {
    int lane = threadIdx.x & 63;
    int wid  = threadIdx.x >> 6;
    int v = blockIdx.x * 4 + wid;
    if (v >= n) return;

    const float2* g2 = (const float2*)g;
    float2 s = g2[v * 64 + lane];            // self-loop term
    float acc0 = s.x, acc1 = s.y;

    int beg = row_start[v], end = row_start[v + 1];
    int e = beg;
    for (; e + 4 <= end; e += 4) {
        int c0 = colv[e], c1 = colv[e + 1], c2 = colv[e + 2], c3 = colv[e + 3];
        float2 a  = g2[c0 * 64 + lane];
        float2 b2 = g2[c1 * 64 + lane];
        float2 c  = g2[c2 * 64 + lane];
        float2 d  = g2[c3 * 64 + lane];
        acc0 += a.x + b2.x + c.x + d.x;
        acc1 += a.y + b2.y + c.y + d.y;
    }
    for (; e < end; ++e) {
        float2 a = g2[colv[e] * 64 + lane];
        acc0 += a.x; acc1 += a.y;
    }

    float dv = dis[v];
    float2 bb = ((const float2*)bias)[lane];
    float2 xp = ((const float2*)xprev)[v * 64 + lane];
    float o0 = fmaxf(fmaf(dv, acc0, bb.x + xp.x), 0.f);
    float o1 = fmaxf(fmaf(dv, acc1, bb.y + xp.y), 0.f);
    ((float2*)xout)[v * 64 + lane] = make_float2(o0, o1);
}

// ---------- host ----------

extern "C" void kernel_launch(void* const* d_in, const int* in_sizes, int n_in,
                              void* d_out, int out_size, void* d_ws, size_t ws_size,
                              hipStream_t stream) {
    const float* x  = (const float*)d_in[0];
    const int*   ei = (const int*)d_in[1];
    const float* W  = (const float*)d_in[2];
    const float* b  = (const float*)d_in[3];
    float* out = (float*)d_out;

    const int n  = in_sizes[0] / EMB;     // 50000
    const int ne = in_sizes[1] / 2;       // 1600000
    const int nlayers = in_sizes[2] / (EMB * EMB);  // 4

    char* ws = (char*)d_ws;
    int*   cnt       = (int*)ws;   ws += (size_t)n * 4;
    int*   row_start = (int*)ws;   ws += (size_t)(n + 1) * 4;
    int*   cursor    = (int*)ws;   ws += (size_t)n * 4;
    float* dis       = (float*)ws; ws += (size_t)n * 4;
    int*   bs        = (int*)ws;   ws += 256 * 4;
    int*   boff      = (int*)ws;   ws += 256 * 4;
    int*   colv      = (int*)ws;   ws += (size_t)ne * 4;
    float* g         = (float*)ws; ws += (size_t)n * EMB * 4;

    int nb = (n + 255) / 256;   // 196 blocks (<=256 required by scan_bs)

    zero_int<<<nb, 256, 0, stream>>>(cnt, n);
    count_deg<<<(ne + 255) / 256, 256, 0, stream>>>(ei, cnt, ne);
    block_sums<<<nb, 256, 0, stream>>>(cnt, bs, n);
    scan_bs<<<1, 256, 0, stream>>>(bs, boff, nb);
    scan_write<<<nb, 256, 0, stream>>>(cnt, boff, row_start, cursor, dis, n);
    fill_col<<<(ne + 255) / 256, 256, 0, stream>>>(ei, cursor, colv, ne);

    for (int l = 0; l < nlayers; ++l) {
        const float* X = (l == 0) ? x : out;   // layer input (also residual)
        gemm_scale<<<512, 256, 0, stream>>>(X, W + (size_t)l * EMB * EMB, dis, g, n);
        aggregate<<<(n + 3) / 4, 256, 0, stream>>>(g, colv, row_start, dis,
                                                   b + (size_t)l * EMB, X, out, n);
    }
}

// Round 2
// 551.920 us; speedup vs baseline: 2.8537x; 2.8537x over previous
//
#include <hip/hip_runtime.h>

// GCN forward: 4 layers of x = relu( D^-1/2 (A+I) D^-1/2 (x W) + b + x )
//   g   = bf16( dis ⊙ (x @ W) )      -- bf16 MFMA GEMM, swapped operands
//   out = relu( dis[v]*(g[v] + Σ_{e:dst=v} g[src_e]) + b + x_prev[v] )
// CSR-by-dst built once per call -> aggregation is pure gather (no fp atomics).
// Messages g kept in bf16 to halve the L3-bound gather traffic; residual
// stream and accumulation stay f32.

#define EMB 128

typedef __attribute__((ext_vector_type(8))) short short8;
typedef __attribute__((ext_vector_type(4))) float f32x4;

__device__ inline unsigned short f2bf(float f) {           // RNE f32 -> bf16
    unsigned int u = __float_as_uint(f);
    return (unsigned short)((u + 0x7fffu + ((u >> 16) & 1u)) >> 16);
}
__device__ inline float bflo(unsigned int u) { return __uint_as_float(u << 16); }
__device__ inline float bfhi(unsigned int u) { return __uint_as_float(u & 0xffff0000u); }

// ---------- setup kernels ----------

__global__ void zero_int(int* __restrict__ p, int n) {
    int i = blockIdx.x * 256 + threadIdx.x;
    if (i < n) p[i] = 0;
}

__global__ void count_deg(const int* __restrict__ ei, int* __restrict__ cnt, int ne) {
    int e = blockIdx.x * 256 + threadIdx.x;
    if (e >= ne) return;
    atomicAdd(&cnt[ei[ne + e]], 1);   // dst row of edge_index
}

__global__ __launch_bounds__(256) void block_sums(const int* __restrict__ cnt,
                                                  int* __restrict__ bs, int n) {
    __shared__ int sm[256];
    int i = blockIdx.x * 256 + threadIdx.x;
    sm[threadIdx.x] = (i < n) ? cnt[i] : 0;
    __syncthreads();
    for (int s = 128; s > 0; s >>= 1) {
        if (threadIdx.x < s) sm[threadIdx.x] += sm[threadIdx.x + s];
        __syncthreads();
    }
    if (threadIdx.x == 0) bs[blockIdx.x] = sm[0];
}

// single block: scan of nb (<=256) block sums -> exclusive block offsets
__global__ __launch_bounds__(256) void scan_bs(const int* __restrict__ bs,
                                               int* __restrict__ boff, int nb) {
    __shared__ int sm[256];
    int t = threadIdx.x;
    sm[t] = (t < nb) ? bs[t] : 0;
    __syncthreads();
    for (int off = 1; off < 256; off <<= 1) {
        int y = (t >= off) ? sm[t - off] : 0;
        __syncthreads();
        sm[t] += y;
        __syncthreads();
    }
    if (t < nb) boff[t] = (t == 0) ? 0 : sm[t - 1];
}

__global__ __launch_bounds__(256) void scan_write(const int* __restrict__ cnt,
                                                  const int* __restrict__ boff,
                                                  int* __restrict__ row_start,
                                                  int* __restrict__ cursor,
                                                  float* __restrict__ dis, int n) {
    __shared__ int sm[256];
    int t = threadIdx.x;
    int i = blockIdx.x * 256 + t;
    int c = (i < n) ? cnt[i] : 0;
    sm[t] = c;
    __syncthreads();
    for (int off = 1; off < 256; off <<= 1) {
        int y = (t >= off) ? sm[t - off] : 0;
        __syncthreads();
        sm[t] += y;
        __syncthreads();
    }
    if (i < n) {
        int excl = boff[blockIdx.x] + sm[t] - c;
        row_start[i] = excl;
        cursor[i]    = excl;
        dis[i] = rsqrtf((float)(c + 1));   // +1 self-loop; always > 0
        if (i == n - 1) row_start[n] = boff[blockIdx.x] + sm[t];
    }
}

__global__ void fill_col(const int* __restrict__ ei, int* __restrict__ cursor,
                         int* __restrict__ colv, int ne) {
    int e = blockIdx.x * 256 + threadIdx.x;
    if (e >= ne) return;
    int s = ei[e];
    int d = ei[ne + e];
    int p = atomicAdd(&cursor[d], 1);
    colv[p] = s;
}

// ---------- bf16 prep ----------

// Pack all layers' W into MFMA A-operand fragment order (W^T chunks).
// frag element f = ((ct*4+ks)*64 + lane)*8 + i  ->  W[k = ks*32+(lane>>4)*8+i][col = ct*16+(lane&15)]
__global__ void pack_w(const float* __restrict__ W, unsigned short* __restrict__ Wp, int total) {
    int t = blockIdx.x * 256 + threadIdx.x;
    if (t >= total) return;
    int layer = t >> 14, f = t & 16383;
    int i  = f & 7;
    int l  = (f >> 3) & 63;
    int ks = (f >> 9) & 3;
    int ct = f >> 11;
    int k   = ks * 32 + (l >> 4) * 8 + i;
    int col = ct * 16 + (l & 15);
    Wp[t] = f2bf(W[layer * 16384 + k * 128 + col]);
}

__global__ void convert_x(const float* __restrict__ x, unsigned short* __restrict__ xb, int n4) {
    int t = blockIdx.x * 256 + threadIdx.x;
    if (t >= n4) return;
    float4 v = ((const float4*)x)[t];
    ushort4 o;
    o.x = f2bf(v.x); o.y = f2bf(v.y); o.z = f2bf(v.z); o.w = f2bf(v.w);
    ((ushort4*)xb)[t] = o;
}

// ---------- per-layer kernels ----------

// g[r] = bf16( dis[r] * (X[r] @ W) ).  One wave computes 32 rows x 128 cols.
// Swapped operands: A = W^T frags (from LDS), B = X row frags (from global).
// D[m=n-dim][c=row]: lane holds rows r=rbase+rt*16+(lane&15), dims nq..nq+3.
__global__ __launch_bounds__(256) void gemm_mfma(const unsigned short* __restrict__ Xb,
                                                 const unsigned short* __restrict__ Wp,
                                                 const float* __restrict__ dis,
                                                 unsigned short* __restrict__ g, int n) {
    __shared__ unsigned short wl[16384];   // 32 KB packed W frags
    {
        const float4* s = (const float4*)Wp;
        float4* d = (float4*)wl;
        #pragma unroll
        for (int i = 0; i < 8; ++i)
            d[i * 256 + threadIdx.x] = s[i * 256 + threadIdx.x];
    }
    __syncthreads();

    int lane = threadIdx.x & 63, wid = threadIdx.x >> 6;
    int rbase = (blockIdx.x * 4 + wid) * 32;
    if (rbase >= n) return;

    int r0 = rbase + (lane & 15);
    int r1 = r0 + 16;
    int kq = (lane >> 4) * 8;

    short8 xf[2][4];
    #pragma unroll
    for (int rt = 0; rt < 2; ++rt) {
        int r = (rt == 0) ? r0 : r1;
        r = min(r, n - 1);
        const unsigned short* p = Xb + (size_t)r * EMB + kq;
        #pragma unroll
        for (int ks = 0; ks < 4; ++ks)
            xf[rt][ks] = *(const short8*)(p + ks * 32);
    }

    f32x4 acc[8][2];
    #pragma unroll
    for (int ct = 0; ct < 8; ++ct) {
        acc[ct][0] = (f32x4){0.f, 0.f, 0.f, 0.f};
        acc[ct][1] = (f32x4){0.f, 0.f, 0.f, 0.f};
    }

    #pragma unroll
    for (int ks = 0; ks < 4; ++ks) {
        #pragma unroll
        for (int ct = 0; ct < 8; ++ct) {
            short8 wf = *(const short8*)(wl + ((ct * 4 + ks) * 64 + lane) * 8);
            acc[ct][0] = __builtin_amdgcn_mfma_f32_16x16x32_bf16(wf, xf[0][ks], acc[ct][0], 0, 0, 0);
            acc[ct][1] = __builtin_amdgcn_mfma_f32_16x16x32_bf16(wf, xf[1][ks], acc[ct][1], 0, 0, 0);
        }
    }

    int nq = (lane >> 4) * 4;
    #pragma unroll
    for (int rt = 0; rt < 2; ++rt) {
        int r = (rt == 0) ? r0 : r1;
        if (r < n) {
            float dv = dis[r];
            #pragma unroll
            for (int ct = 0; ct < 8; ++ct) {
                f32x4 a = acc[ct][rt];
                ushort4 o;
                o.x = f2bf(dv * a[0]);
                o.y = f2bf(dv * a[1]);
                o.z = f2bf(dv * a[2]);
                o.w = f2bf(dv * a[3]);
                *(ushort4*)(g + (size_t)r * EMB + ct * 16 + nq) = o;
            }
        }
    }
}

// out[v] = relu( dis[v]*(g[v] + sum_{e in CSR[v]} g[col[e]]) + b + xprev[v] )
// g is bf16; each lane owns 2 dims (one 4B load per gathered row).
// Also emits bf16 copy of out for the next layer's GEMM input.
__global__ __launch_bounds__(256) void aggregate(const unsigned short* __restrict__ g,
                                                 const int* __restrict__ colv,
                                                 const int* __restrict__ row_start,
                                                 const float* __restrict__ dis,
                                                 const float* __restrict__ bias,
                                                 const float* __restrict__ xprev,
                                                 float* __restrict__ xout,
                                                 unsigned short* __restrict__ xb, int n) {
    int lane = threadIdx.x & 63;
    int wid  = threadIdx.x >> 6;
    int v = blockIdx.x * 4 + wid;
    if (v >= n) return;

    const unsigned int* g1 = (const unsigned int*)g;
    unsigned int su = g1[(size_t)v * 64 + lane];          // self-loop term
    float acc0 = bflo(su), acc1 = bfhi(su);

    int beg = row_start[v], end = row_start[v + 1];
    int e = beg;
    for (; e + 4 <= end; e += 4) {
        int c0 = colv[e], c1 = colv[e + 1], c2 = colv[e + 2], c3 = colv[e + 3];
        unsigned int a = g1[(size_t)c0 * 64 + lane];
        unsigned int b = g1[(size_t)c1 * 64 + lane];
        unsigned int c = g1[(size_t)c2 * 64 + lane];
        unsigned int d = g1[(size_t)c3 * 64 + lane];
        acc0 += bflo(a) + bflo(b) + bflo(c) + bflo(d);
        acc1 += bfhi(a) + bfhi(b) + bfhi(c) + bfhi(d);
    }
    for (; e < end; ++e) {
        unsigned int a = g1[(size_t)colv[e] * 64 + lane];
        acc0 += bflo(a); acc1 += bfhi(a);
    }

    float dv = dis[v];
    float2 bb = ((const float2*)bias)[lane];
    float2 xp = ((const float2*)xprev)[(size_t)v * 64 + lane];
    float o0 = fmaxf(fmaf(dv, acc0, bb.x + xp.x), 0.f);
    float o1 = fmaxf(fmaf(dv, acc1, bb.y + xp.y), 0.f);
    ((float2*)xout)[(size_t)v * 64 + lane] = make_float2(o0, o1);
    unsigned int ob = (unsigned int)f2bf(o0) | ((unsigned int)f2bf(o1) << 16);
    ((unsigned int*)xb)[(size_t)v * 64 + lane] = ob;
}

// ---------- host ----------

extern "C" void kernel_launch(void* const* d_in, const int* in_sizes, int n_in,
                              void* d_out, int out_size, void* d_ws, size_t ws_size,
                              hipStream_t stream) {
    const float* x  = (const float*)d_in[0];
    const int*   ei = (const int*)d_in[1];
    const float* W  = (const float*)d_in[2];
    const float* b  = (const float*)d_in[3];
    float* out = (float*)d_out;

    const int n  = in_sizes[0] / EMB;               // 50000
    const int ne = in_sizes[1] / 2;                 // 1600000
    const int nlayers = in_sizes[2] / (EMB * EMB);  // 4

    char* ws = (char*)d_ws;
    int*   cnt       = (int*)ws;   ws += (size_t)n * 4;
    int*   row_start = (int*)ws;   ws += (size_t)(n + 1) * 4;
    int*   cursor    = (int*)ws;   ws += (size_t)n * 4;
    float* dis       = (float*)ws; ws += (size_t)n * 4;
    int*   bs        = (int*)ws;   ws += 256 * 4;
    int*   boff      = (int*)ws;   ws += 256 * 4;
    int*   colv      = (int*)ws;   ws += (size_t)ne * 4;
    unsigned short* g  = (unsigned short*)ws; ws += (size_t)n * EMB * 2;
    unsigned short* xb = (unsigned short*)ws; ws += (size_t)n * EMB * 2;
    unsigned short* Wp = (unsigned short*)ws; ws += (size_t)nlayers * 16384 * 2;

    int nb = (n + 255) / 256;   // 196 blocks (<=256 required by scan_bs)

    zero_int<<<nb, 256, 0, stream>>>(cnt, n);
    count_deg<<<(ne + 255) / 256, 256, 0, stream>>>(ei, cnt, ne);
    block_sums<<<nb, 256, 0, stream>>>(cnt, bs, n);
    scan_bs<<<1, 256, 0, stream>>>(bs, boff, nb);
    scan_write<<<nb, 256, 0, stream>>>(cnt, boff, row_start, cursor, dis, n);
    fill_col<<<(ne + 255) / 256, 256, 0, stream>>>(ei, cursor, colv, ne);

    int wtotal = nlayers * 16384;
    pack_w<<<(wtotal + 255) / 256, 256, 0, stream>>>(W, Wp, wtotal);
    convert_x<<<(n * 32 + 255) / 256, 256, 0, stream>>>(x, xb, n * 32);

    int gemm_blocks = (n + 127) / 128;   // 4 waves/block, 32 rows/wave
    for (int l = 0; l < nlayers; ++l) {
        const float* Xf = (l == 0) ? x : out;   // f32 residual stream
        gemm_mfma<<<gemm_blocks, 256, 0, stream>>>(xb, Wp + (size_t)l * 16384, dis, g, n);
        aggregate<<<(n + 3) / 4, 256, 0, stream>>>(g, colv, row_start, dis,
                                                   b + (size_t)l * EMB, Xf, out, xb, n);
    }
}